// Round 8
// baseline (66.860 us; speedup 1.0000x reference)
//
#include <hip/hip_runtime.h>

#define NPIX 16384
#define WIDTH 128
#define APT 16           // A-points per thread
#define ABLK (256 * APT) // 4096 A-points per block
#define TILE 64          // B-points staged per LDS tile

typedef float v2f __attribute__((ext_vector_type(2)));
typedef float v4f __attribute__((ext_vector_type(4)));

// Packed-FP32 FMA (VOP3P): all operands are 64-bit VGPR pairs. op_sel /
// op_sel_hi select which 32-bit dword of src0 feeds the low/high result —
// broadcast-lo: both halves read src0.lo; broadcast-hi: both read src0.hi.
__device__ __forceinline__ v2f pk_fma_blo(v2f a, v2f b, v2f c) {
    v2f d;
    asm("v_pk_fma_f32 %0, %1, %2, %3 op_sel:[0,0,0] op_sel_hi:[0,1,1]"
        : "=v"(d) : "v"(a), "v"(b), "v"(c));
    return d;
}
__device__ __forceinline__ v2f pk_fma_bhi(v2f a, v2f b, v2f c) {
    v2f d;
    asm("v_pk_fma_f32 %0, %1, %2, %3 op_sel:[1,0,0] op_sel_hi:[1,1,1]"
        : "=v"(d) : "v"(a), "v"(b), "v"(c));
    return d;
}

__device__ __forceinline__ float min3f(float a, float b, float c) {
    float d;
    asm("v_min3_f32 %0, %1, %2, %3" : "=v"(d) : "v"(a), "v"(b), "v"(c));
    return d;
}

// depth -> (x, y, z, |p|^2 + inf_add). Same math as reference pixel2xyz.
__device__ __forceinline__ float4 make_point(float d, int p,
    float fu, float cu, float p03, float fv, float cv, float p13, float p23,
    float inf_add) {
    float px = (float)(p & (WIDTH - 1));
    float py = (float)(p >> 7);
    float x = (px * (d + p23) - (cu * d + p03)) / fu;
    float y = (py * (d + p23) - (cv * d + p13)) / fv;
    float s = x * x + y * y + d * d;
    return make_float4(x, y, d, s + inf_add);
}

// ---------------------------------------------------------------------------
// Pairwise-min kernel (precompute fused). Each block: 4096 A-points
// (16/thread). A-state packed for op_sel broadcast: axy[k]=(-2ax,-2ay) pair,
// azp[k/2]=(az_k, az_{k+1}) pair -> 4 VGPR per A-point. B staged in LDS
// pair-interleaved: sP0[q]=(b0x,b1x,b0y,b1y), sP1[q]=(b0z,b1z,b0w,b1w);
// 2 broadcast ds_read_b128 per 2 B-points. Inner: per 2A x 2B = 6 v_pk_fma_f32
// + 2 v_min3_f32 = 2.0 VALU instr/pair, forced via inline asm. Invalid pixels
// (target<=0) carry +1e30 in w -> masked pairs lose the min. |a|^2 added back
// in reduce. No atomics (R4 lesson).
// ---------------------------------------------------------------------------
__global__ __launch_bounds__(256, 4) void pair_min_kernel(
    const float* __restrict__ pred,
    const float* __restrict__ target,
    const float* __restrict__ P,
    float* __restrict__ pm12,
    float* __restrict__ pm21,
    int jlen) {
    float fu = P[0], cu = P[2], p03 = P[3];
    float fv = P[5], cv = P[6], p13 = P[7], p23 = P[11];

    const float* __restrict__ dA;
    const float* __restrict__ dB;
    float* __restrict__ pm;
    if (blockIdx.z == 0) { dA = target; dB = pred;   pm = pm12; }
    else                 { dA = pred;   dB = target; pm = pm21; }

    __shared__ float sP0f[TILE * 2]; // (b0x,b1x,b0y,b1y) per pair
    __shared__ float sP1f[TILE * 2]; // (b0z,b1z,b0w,b1w) per pair
    const v4f* sP0 = (const v4f*)sP0f;
    const v4f* sP1 = (const v4f*)sP1f;
    int t = threadIdx.x;

    // A points: 16 per thread; -2 folded; packed pairs for op_sel broadcast.
    int abase = blockIdx.x * ABLK + t;
    v2f axy[APT];
    v2f azp[APT / 2];
    float mn[APT];
    #pragma unroll
    for (int k = 0; k < APT; ++k) {
        int a = abase + k * 256;
        float4 pa = make_point(dA[a], a, fu, cu, p03, fv, cv, p13, p23, 0.0f);
        axy[k].x = -2.0f * pa.x;
        axy[k].y = -2.0f * pa.y;
        if (k & 1) azp[k >> 1].y = -2.0f * pa.z;
        else       azp[k >> 1].x = -2.0f * pa.z;
        mn[k] = 3e38f;
    }

    int jbase = blockIdx.y * jlen;
    for (int jt = 0; jt < jlen; jt += TILE) {
        __syncthreads();
        if (t < TILE) {
            int jb = jbase + jt + t;
            float tb = target[jb];
            float inf_add = (tb > 0.0f) ? 0.0f : 1e30f;
            float4 b = make_point(dB[jb], jb, fu, cu, p03, fv, cv, p13, p23, inf_add);
            int q = t >> 1, r = t & 1;
            sP0f[4 * q + r]     = b.x;
            sP0f[4 * q + 2 + r] = b.y;
            sP1f[4 * q + r]     = b.z;
            sP1f[4 * q + 2 + r] = b.w;
        }
        __syncthreads();

        #pragma unroll 2
        for (int p = 0; p < TILE / 2; ++p) {
            v4f c0 = sP0[p]; // broadcast ds_read_b128
            v4f c1 = sP1[p];
            v2f bx = c0.lo, by = c0.hi;
            v2f bz = c1.lo, bw = c1.hi;
            #pragma unroll
            for (int k = 0; k < APT; k += 2) {
                // A-point k: az in azp[k/2].lo
                v2f e0 = pk_fma_blo(azp[k >> 1], bz, bw);
                e0 = pk_fma_blo(axy[k], bx, e0);
                e0 = pk_fma_bhi(axy[k], by, e0);
                mn[k] = min3f(e0.x, e0.y, mn[k]);
                // A-point k+1: az in azp[k/2].hi
                v2f e1 = pk_fma_bhi(azp[k >> 1], bz, bw);
                e1 = pk_fma_blo(axy[k + 1], bx, e1);
                e1 = pk_fma_bhi(axy[k + 1], by, e1);
                mn[k + 1] = min3f(e1.x, e1.y, mn[k + 1]);
            }
        }
    }

    int obase = blockIdx.y * NPIX + abase;
    #pragma unroll
    for (int k = 0; k < APT; ++k) pm[obase + k * 256] = mn[k];
}

// ---------------------------------------------------------------------------
// Reduce: 256 blocks; each owns 64 A-points, threads split the JC slices
// 4-way (min exactly associative), LDS-combine, |a|^2 add-back, masked
// deterministic sum. Recomputes |a|^2 from depth.
// ---------------------------------------------------------------------------
__global__ __launch_bounds__(256) void reduce_kernel(
    const float* __restrict__ pm12,
    const float* __restrict__ pm21,
    const float* __restrict__ pred,
    const float* __restrict__ target,
    const float* __restrict__ P,
    int jc,
    float* __restrict__ bsum,
    float* __restrict__ bn) {
    int t = threadIdx.x;
    int al = t & 63, q = t >> 6;
    int a = blockIdx.x * 64 + al;

    float m12 = 3e38f, m21 = 3e38f;
    int per = jc >> 2;
    int jc0 = q * per;
    for (int j = jc0; j < jc0 + per; ++j) {
        m12 = fminf(m12, pm12[j * NPIX + a]);
        m21 = fminf(m21, pm21[j * NPIX + a]);
    }
    __shared__ float s12[4][64], s21[4][64];
    s12[q][al] = m12;
    s21[q][al] = m21;
    __syncthreads();

    if (t < 64) {
        m12 = fminf(fminf(s12[0][t], s12[1][t]), fminf(s12[2][t], s12[3][t]));
        m21 = fminf(fminf(s21[0][t], s21[1][t]), fminf(s21[2][t], s21[3][t]));

        float fu = P[0], cu = P[2], p03 = P[3];
        float fv = P[5], cv = P[6], p13 = P[7], p23 = P[11];
        float dt = target[a], dp = pred[a];
        float v = (dt > 0.0f) ? 1.0f : 0.0f;
        float4 pT = make_point(dt, a, fu, cu, p03, fv, cv, p13, p23, 0.0f);
        float4 pP = make_point(dp, a, fu, cu, p03, fv, cv, p13, p23, 0.0f);
        float contrib = v * ((m12 + pT.w) + (m21 + pP.w));

        for (int o = 32; o > 0; o >>= 1) {
            contrib += __shfl_down(contrib, o);
            v += __shfl_down(v, o);
        }
        if (t == 0) {
            bsum[blockIdx.x] = contrib;
            bn[blockIdx.x] = v;
        }
    }
}

// ---------------------------------------------------------------------------
// Final: fixed-order lane-parallel sum of 256 partials (deterministic).
// ---------------------------------------------------------------------------
__global__ void final_kernel(const float* __restrict__ bsum,
                             const float* __restrict__ bn,
                             float* __restrict__ out) {
    int t = threadIdx.x; // 64 threads
    float s = 0.0f, n = 0.0f;
    for (int i = t; i < 256; i += 64) { s += bsum[i]; n += bn[i]; }
    for (int o = 32; o > 0; o >>= 1) {
        s += __shfl_down(s, o);
        n += __shfl_down(n, o);
    }
    if (t == 0) out[0] = s / n;
}

extern "C" void kernel_launch(void* const* d_in, const int* in_sizes, int n_in,
                              void* d_out, int out_size, void* d_ws, size_t ws_size,
                              hipStream_t stream) {
    const float* pred   = (const float*)d_in[0];
    const float* target = (const float*)d_in[1];
    const float* P      = (const float*)d_in[2];
    float* out = (float*)d_out;

    // choose J-slice count that fits the workspace (deterministic given ws_size)
    int JC = 128;
    while (JC > 1 && (size_t)2 * JC * NPIX * 4 + 2048 > ws_size) JC >>= 1;

    char* ws = (char*)d_ws;
    float* pm12 = (float*)ws;                 // JC*NPIX floats
    float* pm21 = pm12 + (size_t)JC * NPIX;
    float* bsum = pm21 + (size_t)JC * NPIX;   // 256 + 256
    float* bn   = bsum + 256;

    int jlen = NPIX / JC;
    dim3 grid(NPIX / ABLK, JC, 2); // (4, 128, 2) = 1024 blocks at JC=128
    pair_min_kernel<<<grid, 256, 0, stream>>>(pred, target, P, pm12, pm21, jlen);

    reduce_kernel<<<dim3(256), 256, 0, stream>>>(pm12, pm21, pred, target, P, JC, bsum, bn);
    final_kernel<<<1, 64, 0, stream>>>(bsum, bn, out);
}